// Round 16
// baseline (87.435 us; speedup 1.0000x reference)
//
#include <hip/hip_runtime.h>

#define MODES 10
#define NPH 5
#define DEPTH 10
#define NST5 2002
#define BATCH 4096
#define KSPLIT 16
#define KCHUNK 128

// Module-scope scratch: allocated at .so load, fully rewritten every call.
// Transition table, per level k (k=0..4), layout [t][slot] with k+1 slots:
//   lo32 = parent_idx | (j << 12);  hi32 = f32 bits of sqrt(occ)
//   padding entries are all-zero (sq = 0.0f adds nothing).
__device__ unsigned long long g_tbl64[13650];
__device__ float2 g_M[MODES][NPH];       // batch-independent mesh matrix cols 0..4
__device__ float g_probs[(size_t)BATCH * NST5];
__device__ float g_part[(size_t)KSPLIT * BATCH * 64];

// ---------- combinatorics ----------
// count(m, n) = C(n+m-1, m-1), m in [1,10], n in [0,5] -> exact constant LUT
// (i64 mul/div loop here previously made k_tables 134 us: soft i64 divide).
__device__ __forceinline__ int d_count(int m, int n) {
    static const unsigned short C[11][6] = {
        {0, 0, 0, 0, 0, 0},
        {1, 1, 1, 1, 1, 1},
        {1, 2, 3, 4, 5, 6},
        {1, 3, 6, 10, 15, 21},
        {1, 4, 10, 20, 35, 56},
        {1, 5, 15, 35, 70, 126},
        {1, 6, 21, 56, 126, 252},
        {1, 7, 28, 84, 210, 462},
        {1, 8, 36, 120, 330, 792},
        {1, 9, 45, 165, 495, 1287},
        {1, 10, 55, 220, 715, 2002},
    };
    return C[m][n];
}

__device__ void d_unrank(int r, int n, int* s) {
    for (int p = 0; p < MODES; p++) {
        int mm = MODES - p;
        if (mm == 1) { s[p] = n; return; }
        int k = n;
        for (; k >= 0; k--) {
            int c = d_count(mm - 1, n - k);
            if (r < c) break;
            r -= c;
        }
        s[p] = k; n -= k;
    }
}

__device__ int d_rank(const int* s, int n) {
    int r = 0;
    for (int p = 0; p < MODES && n > 0; p++) {
        int mm = MODES - p;
        if (mm == 1) break;
        for (int k = n; k > s[p]; k--) r += d_count(mm - 1, n - k);
        n -= s[p];
    }
    return r;
}

__global__ void k_tables() {
    int id = blockIdx.x * 256 + threadIdx.x;
    if (id >= 3002) return;
    const int sizes[5]  = {10, 55, 220, 715, 2002};
    const int base64[5] = {0, 10, 120, 780, 3640};
    int k = 0, t = id;
    while (k < 5 && t >= sizes[k]) { t -= sizes[k]; k++; }
    int s[10];
    d_unrank(t, k + 1, s);
    unsigned long long* tt = g_tbl64 + base64[k] + (size_t)t * (k + 1);
    int slot = 0;
    for (int j = 0; j < MODES; j++) {
        if (s[j] > 0) {
            s[j]--;
            int p = d_rank(s, k);
            s[j]++;
            unsigned meta = (unsigned)p | ((unsigned)j << 12);
            unsigned sqb = __float_as_uint(sqrtf((float)s[j]));
            tt[slot] = (unsigned long long)meta | ((unsigned long long)sqb << 32);
            slot++;
        }
    }
    for (; slot < k + 1; slot++) tt[slot] = 0ull;
}

// ---------- batch-independent mesh matrix M = BS9 D9 ... BS1 D1 BS0 ----------
// (U_b = M . diag(e^{i 2 pi x_b}); SLOS only uses columns 0..4.)
__global__ void k_prep(const float* __restrict__ theta) {
    __shared__ float2 Ush[MODES][NPH];
    const int tid = threadIdx.x;
    const int r = tid / 5, c = tid % 5;
    const bool act = (tid < 50);
    float2 val = make_float2((act && r == c) ? 1.f : 0.f, 0.f);
    for (int l = 0; l < DEPTH; l++) {
        if (act && l > 0) {
            float ang = theta[(l - 1) * MODES + r];
            float s_, c_; sincosf(ang, &s_, &c_);
            float nx = val.x * c_ - val.y * s_;
            float ny = val.x * s_ + val.y * c_;
            val = make_float2(nx, ny);
        }
        if (act) Ush[r][c] = val;
        __syncthreads();
        float2 nv = val;
        if (act) {
            int o = l & 1;
            int lo = r - o;
            int partner = o + (lo ^ 1);
            if (lo >= 0 && partner < MODES) {
                float2 pb = Ush[partner][c];
                const float inv = 0.70710678118654752f;
                nv.x = inv * (val.x - pb.y);
                nv.y = inv * (val.y + pb.x);
            }
        }
        __syncthreads();
        val = nv;
    }
    if (act) g_M[r][c] = val;
}

// ---------- SLOS level: S = k+1 slots per target, 2 batch elems packed ----------
template<int S>
__device__ __forceinline__ void slos_level(const float4* __restrict__ src,
                                           float4* __restrict__ dst,
                                           const unsigned long long* __restrict__ tk,
                                           int N, int tid,
                                           const float4 (*Ush2)[NPH], int k) {
    for (int t = tid; t < N; t += 256) {
        float ax0 = 0.f, ay0 = 0.f, ax1 = 0.f, ay1 = 0.f;
        const unsigned long long* tt = tk + (size_t)t * S;
        #pragma unroll
        for (int sl = 0; sl < S; sl++) {
            unsigned long long e = tt[sl];
            unsigned lo = (unsigned)e;
            float sq = __uint_as_float((unsigned)(e >> 32));
            int idx = lo & 0xFFF;
            int j = (lo >> 12) & 0xF;
            float4 a = src[idx];
            float4 u = Ush2[j][k];
            float tx0 = u.x * a.x - u.y * a.y;
            float ty0 = u.x * a.y + u.y * a.x;
            ax0 = fmaf(sq, tx0, ax0);
            ay0 = fmaf(sq, ty0, ay0);
            float tx1 = u.z * a.z - u.w * a.w;
            float ty1 = u.z * a.w + u.w * a.z;
            ax1 = fmaf(sq, tx1, ax1);
            ay1 = fmaf(sq, ty1, ay1);
        }
        dst[t] = make_float4(ax0, ay0, ax1, ay1);
    }
    __syncthreads();
}

// ---------- SLOS, 2 batch elements per block ----------
__global__ __launch_bounds__(256)
void k_slos(const float* __restrict__ x) {
    __shared__ float4 Ush2[MODES][NPH];  // (b0.re, b0.im, b1.re, b1.im)
    __shared__ float4 ampA2[715];
    __shared__ float4 ampB2[220];

    const int b0 = blockIdx.x * 2;
    const int tid = threadIdx.x;
    const int r = tid / 5, c = tid % 5;

    if (tid < 50) {
        float a0 = 6.28318530717958647692f * x[b0 * MODES + c];
        float a1 = 6.28318530717958647692f * x[(b0 + 1) * MODES + c];
        float s0, c0, s1, c1;
        sincosf(a0, &s0, &c0);
        sincosf(a1, &s1, &c1);
        float2 m = g_M[r][c];
        Ush2[r][c] = make_float4(m.x * c0 - m.y * s0, m.x * s0 + m.y * c0,
                                 m.x * c1 - m.y * s1, m.x * s1 + m.y * c1);
    }
    if (tid == 0) ampA2[0] = make_float4(1.f, 0.f, 1.f, 0.f);
    __syncthreads();

    slos_level<1>(ampA2, ampB2, g_tbl64 + 0,   10,  tid, Ush2, 0);
    slos_level<2>(ampB2, ampA2, g_tbl64 + 10,  55,  tid, Ush2, 1);
    slos_level<3>(ampA2, ampB2, g_tbl64 + 120, 220, tid, Ush2, 2);
    slos_level<4>(ampB2, ampA2, g_tbl64 + 780, 715, tid, Ush2, 3);

    // level 4 fused with |.|^2 -> global (no LDS round-trip)
    float* po0 = g_probs + (size_t)b0 * NST5;
    float* po1 = po0 + NST5;
    const unsigned long long* tk = g_tbl64 + 3640;
    for (int t = tid; t < NST5; t += 256) {
        float ax0 = 0.f, ay0 = 0.f, ax1 = 0.f, ay1 = 0.f;
        const unsigned long long* tt = tk + (size_t)t * 5;
        #pragma unroll
        for (int sl = 0; sl < 5; sl++) {
            unsigned long long e = tt[sl];
            unsigned lo = (unsigned)e;
            float sq = __uint_as_float((unsigned)(e >> 32));
            int idx = lo & 0xFFF;
            int j = (lo >> 12) & 0xF;
            float4 a = ampA2[idx];
            float4 u = Ush2[j][4];
            float tx0 = u.x * a.x - u.y * a.y;
            float ty0 = u.x * a.y + u.y * a.x;
            ax0 = fmaf(sq, tx0, ax0);
            ay0 = fmaf(sq, ty0, ay0);
            float tx1 = u.z * a.z - u.w * a.w;
            float ty1 = u.z * a.w + u.w * a.z;
            ax1 = fmaf(sq, tx1, ax1);
            ay1 = fmaf(sq, ty1, ay1);
        }
        po0[t] = ax0 * ax0 + ay0 * ay0;
        po1[t] = ax1 * ax1 + ay1 * ay1;
    }
}

// ---------- GEMM: g_part[kc] = P[64-row tile] x W  (LDS-tiled, K split x16) ----------
// Inner loop in kk-steps of 4: all-float4 LDS reads (8 loads + 64 FMA per step)
// instead of 20 loads + 64 FMA; per-acc accumulation order stays kk-ascending
// (bit-identical output).
__global__ __launch_bounds__(256)
void k_gemm2(const float* __restrict__ W) {
    __shared__ float P_lds[64][68];
    __shared__ float W_lds[64][68];

    const int bm = blockIdx.x;
    const int kc = blockIdx.y;
    const int r0 = bm * 64;
    const int ks = kc * KCHUNK;
    const int ke = (ks + KCHUNK < NST5) ? ks + KCHUNK : NST5;

    const int tid = threadIdx.x;
    const int rg = tid >> 4;
    const int cg = tid & 15;
    const int srow = tid >> 4;
    const int sc4 = (tid & 15) * 4;

    float acc[4][4];
    #pragma unroll
    for (int i = 0; i < 4; i++)
        #pragma unroll
        for (int j = 0; j < 4; j++) acc[i][j] = 0.f;

    for (int k0 = ks; k0 < ke; k0 += 64) {
        const int kw = ke - k0;           // >=64 means fully valid
        __syncthreads();
        #pragma unroll
        for (int p = 0; p < 4; p++) {
            int row = p * 16 + srow;
            float4 v = make_float4(0.f, 0.f, 0.f, 0.f);
            if (sc4 < kw) {
                const float* src = &g_probs[(size_t)(r0 + row) * NST5 + k0 + sc4];
                if (sc4 + 4 <= kw) {
                    v = *(const float4*)src;
                } else {
                    float tmp[4] = {0.f, 0.f, 0.f, 0.f};
                    for (int i = 0; i < kw - sc4; i++) tmp[i] = src[i];
                    v = *(const float4*)tmp;
                }
            }
            *(float4*)&P_lds[row][sc4] = v;
        }
        #pragma unroll
        for (int p = 0; p < 4; p++) {
            int krow = p * 16 + srow;
            float4 v = make_float4(0.f, 0.f, 0.f, 0.f);
            if (krow < kw)
                v = *(const float4*)&W[(size_t)(k0 + krow) * 64 + sc4];
            *(float4*)&W_lds[krow][sc4] = v;
        }
        __syncthreads();

        #pragma unroll 2
        for (int kk0 = 0; kk0 < 64; kk0 += 4) {
            float4 pr[4];
            #pragma unroll
            for (int i = 0; i < 4; i++)
                pr[i] = *(const float4*)&P_lds[rg * 4 + i][kk0];
            float4 wv[4];
            #pragma unroll
            for (int q = 0; q < 4; q++)
                wv[q] = *(const float4*)&W_lds[kk0 + q][cg * 4];
            #pragma unroll
            for (int i = 0; i < 4; i++) {
                acc[i][0] = fmaf(pr[i].x, wv[0].x, acc[i][0]);
                acc[i][1] = fmaf(pr[i].x, wv[0].y, acc[i][1]);
                acc[i][2] = fmaf(pr[i].x, wv[0].z, acc[i][2]);
                acc[i][3] = fmaf(pr[i].x, wv[0].w, acc[i][3]);
                acc[i][0] = fmaf(pr[i].y, wv[1].x, acc[i][0]);
                acc[i][1] = fmaf(pr[i].y, wv[1].y, acc[i][1]);
                acc[i][2] = fmaf(pr[i].y, wv[1].z, acc[i][2]);
                acc[i][3] = fmaf(pr[i].y, wv[1].w, acc[i][3]);
                acc[i][0] = fmaf(pr[i].z, wv[2].x, acc[i][0]);
                acc[i][1] = fmaf(pr[i].z, wv[2].y, acc[i][1]);
                acc[i][2] = fmaf(pr[i].z, wv[2].z, acc[i][2]);
                acc[i][3] = fmaf(pr[i].z, wv[2].w, acc[i][3]);
                acc[i][0] = fmaf(pr[i].w, wv[3].x, acc[i][0]);
                acc[i][1] = fmaf(pr[i].w, wv[3].y, acc[i][1]);
                acc[i][2] = fmaf(pr[i].w, wv[3].z, acc[i][2]);
                acc[i][3] = fmaf(pr[i].w, wv[3].w, acc[i][3]);
            }
        }
    }

    float* po = g_part + ((size_t)kc * BATCH + r0) * 64;
    #pragma unroll
    for (int i = 0; i < 4; i++) {
        float4 v = make_float4(acc[i][0], acc[i][1], acc[i][2], acc[i][3]);
        *(float4*)&po[(size_t)(rg * 4 + i) * 64 + cg * 4] = v;
    }
}

// ---------- reduce KSPLIT partials + bias ----------
__global__ __launch_bounds__(256)
void k_reduce(const float* __restrict__ bias, float* __restrict__ out) {
    int i = blockIdx.x * 256 + threadIdx.x;
    const int TOT = BATCH * 64;
    if (i < TOT) {
        float v = bias[i & 63];
        #pragma unroll
        for (int m = 0; m < KSPLIT; m++) v += g_part[(size_t)m * TOT + i];
        out[i] = v;
    }
}

extern "C" void kernel_launch(void* const* d_in, const int* in_sizes, int n_in,
                              void* d_out, int out_size, void* d_ws, size_t ws_size,
                              hipStream_t stream) {
    const float* x     = (const float*)d_in[0];
    const float* theta = (const float*)d_in[1];
    const float* W     = (const float*)d_in[2];
    const float* bias  = (const float*)d_in[3];
    float* out = (float*)d_out;
    (void)d_ws; (void)ws_size; (void)in_sizes; (void)n_in; (void)out_size;

    k_tables<<<12, 256, 0, stream>>>();
    k_prep<<<1, 64, 0, stream>>>(theta);
    k_slos<<<BATCH / 2, 256, 0, stream>>>(x);
    k_gemm2<<<dim3(64, KSPLIT), 256, 0, stream>>>(W);
    k_reduce<<<1024, 256, 0, stream>>>(bias, out);
}

// Round 17
// 83.063 us; speedup vs baseline: 1.0526x; 1.0526x over previous
//
#include <hip/hip_runtime.h>

#define MODES 10
#define NPH 5
#define DEPTH 10
#define NST5 2002
#define BATCH 4096
#define KSPLIT 16
#define KCHUNK 126

// Module-scope scratch: allocated at .so load, fully rewritten every call.
// Factorial-normalized SLOS: b[t] = sum_j U[j,i] b[parent] (no sqrt factor!),
// probs[t] = c2[t] * |b5[t]|^2 with c2[t] = prod_j t_j!  (exact small ints).
// Table: per level k, layout [t][slot], S=k+1 u32 slots: idx | (j<<12).
// Padding slots point at a dedicated always-zero amp entry (A:715, B:220).
__device__ unsigned g_tbl32[13650];
__device__ float g_c2[NST5];
__device__ float2 g_M[MODES][NPH];       // batch-independent mesh matrix cols 0..4
__device__ float g_probs[(size_t)BATCH * NST5];
__device__ float g_part[(size_t)KSPLIT * BATCH * 64];

// ---------- combinatorics ----------
// count(m, n) = C(n+m-1, m-1), m in [1,10], n in [0,5] -> exact constant LUT
// (i64 mul/div loop here previously made k_tables 134 us: soft i64 divide).
__device__ __forceinline__ int d_count(int m, int n) {
    static const unsigned short C[11][6] = {
        {0, 0, 0, 0, 0, 0},
        {1, 1, 1, 1, 1, 1},
        {1, 2, 3, 4, 5, 6},
        {1, 3, 6, 10, 15, 21},
        {1, 4, 10, 20, 35, 56},
        {1, 5, 15, 35, 70, 126},
        {1, 6, 21, 56, 126, 252},
        {1, 7, 28, 84, 210, 462},
        {1, 8, 36, 120, 330, 792},
        {1, 9, 45, 165, 495, 1287},
        {1, 10, 55, 220, 715, 2002},
    };
    return C[m][n];
}

__device__ void d_unrank(int r, int n, int* s) {
    for (int p = 0; p < MODES; p++) {
        int mm = MODES - p;
        if (mm == 1) { s[p] = n; return; }
        int k = n;
        for (; k >= 0; k--) {
            int c = d_count(mm - 1, n - k);
            if (r < c) break;
            r -= c;
        }
        s[p] = k; n -= k;
    }
}

__device__ int d_rank(const int* s, int n) {
    int r = 0;
    for (int p = 0; p < MODES && n > 0; p++) {
        int mm = MODES - p;
        if (mm == 1) break;
        for (int k = n; k > s[p]; k--) r += d_count(mm - 1, n - k);
        n -= s[p];
    }
    return r;
}

__global__ void k_tables() {
    int id = blockIdx.x * 256 + threadIdx.x;
    if (id >= 3002) return;
    const int sizes[5]  = {10, 55, 220, 715, 2002};
    const int base32[5] = {0, 10, 120, 780, 3640};
    // zero-amp index in the SRC buffer of level k (A holds 716, B holds 221)
    const int zidx[5]   = {0, 220, 715, 220, 715};
    int k = 0, t = id;
    while (k < 5 && t >= sizes[k]) { t -= sizes[k]; k++; }
    int s[10];
    d_unrank(t, k + 1, s);
    unsigned* tt = g_tbl32 + base32[k] + (size_t)t * (k + 1);
    int slot = 0;
    for (int j = 0; j < MODES; j++) {
        if (s[j] > 0) {
            s[j]--;
            int p = d_rank(s, k);
            s[j]++;
            tt[slot++] = (unsigned)p | ((unsigned)j << 12);
        }
    }
    for (; slot < k + 1; slot++) tt[slot] = (unsigned)zidx[k];  // j=0, amp=0
    if (k == 4) {
        const float fact[6] = {1.f, 1.f, 2.f, 6.f, 24.f, 120.f};
        float c2 = 1.f;
        for (int j = 0; j < MODES; j++) c2 *= fact[s[j]];
        g_c2[t] = c2;
    }
}

// ---------- batch-independent mesh matrix M = BS9 D9 ... BS1 D1 BS0 ----------
// (U_b = M . diag(e^{i 2 pi x_b}); SLOS only uses columns 0..4.)
__global__ void k_prep(const float* __restrict__ theta) {
    __shared__ float2 Ush[MODES][NPH];
    const int tid = threadIdx.x;
    const int r = tid / 5, c = tid % 5;
    const bool act = (tid < 50);
    float2 val = make_float2((act && r == c) ? 1.f : 0.f, 0.f);
    for (int l = 0; l < DEPTH; l++) {
        if (act && l > 0) {
            float ang = theta[(l - 1) * MODES + r];
            float s_, c_; sincosf(ang, &s_, &c_);
            float nx = val.x * c_ - val.y * s_;
            float ny = val.x * s_ + val.y * c_;
            val = make_float2(nx, ny);
        }
        if (act) Ush[r][c] = val;
        __syncthreads();
        float2 nv = val;
        if (act) {
            int o = l & 1;
            int lo = r - o;
            int partner = o + (lo ^ 1);
            if (lo >= 0 && partner < MODES) {
                float2 pb = Ush[partner][c];
                const float inv = 0.70710678118654752f;
                nv.x = inv * (val.x - pb.y);
                nv.y = inv * (val.y + pb.x);
            }
        }
        __syncthreads();
        val = nv;
    }
    if (act) g_M[r][c] = val;
}

// ---------- SLOS level: S slots/target, 4 batch elems packed ----------
template<int S>
__device__ __forceinline__ void slos4(const float4 (*__restrict__ src)[2],
                                      float4 (*__restrict__ dst)[2],
                                      const unsigned* __restrict__ tk,
                                      int N, int tid,
                                      const float4 (*Ua)[NPH],
                                      const float4 (*Ub)[NPH], int k) {
    for (int t = tid; t < N; t += 256) {
        float ax0 = 0.f, ay0 = 0.f, ax1 = 0.f, ay1 = 0.f;
        float ax2 = 0.f, ay2 = 0.f, ax3 = 0.f, ay3 = 0.f;
        const unsigned* tt = tk + (size_t)t * S;
        #pragma unroll
        for (int sl = 0; sl < S; sl++) {
            unsigned e = tt[sl];
            int idx = e & 0xFFF;
            int j = (e >> 12) & 0xF;
            float4 a01 = src[idx][0];
            float4 a23 = src[idx][1];
            float4 u01 = Ua[j][k];
            float4 u23 = Ub[j][k];
            ax0 = fmaf(u01.x, a01.x, ax0); ax0 = fmaf(-u01.y, a01.y, ax0);
            ay0 = fmaf(u01.x, a01.y, ay0); ay0 = fmaf( u01.y, a01.x, ay0);
            ax1 = fmaf(u01.z, a01.z, ax1); ax1 = fmaf(-u01.w, a01.w, ax1);
            ay1 = fmaf(u01.z, a01.w, ay1); ay1 = fmaf( u01.w, a01.z, ay1);
            ax2 = fmaf(u23.x, a23.x, ax2); ax2 = fmaf(-u23.y, a23.y, ax2);
            ay2 = fmaf(u23.x, a23.y, ay2); ay2 = fmaf( u23.y, a23.x, ay2);
            ax3 = fmaf(u23.z, a23.z, ax3); ax3 = fmaf(-u23.w, a23.w, ax3);
            ay3 = fmaf(u23.z, a23.w, ay3); ay3 = fmaf( u23.w, a23.z, ay3);
        }
        dst[t][0] = make_float4(ax0, ay0, ax1, ay1);
        dst[t][1] = make_float4(ax2, ay2, ax3, ay3);
    }
    __syncthreads();
}

// ---------- SLOS, 4 batch elements per block ----------
__global__ __launch_bounds__(256)
void k_slos(const float* __restrict__ x) {
    __shared__ float4 Ua[MODES][NPH];    // (b0.re, b0.im, b1.re, b1.im)
    __shared__ float4 Ub[MODES][NPH];    // (b2.re, b2.im, b3.re, b3.im)
    __shared__ float4 ampA[716][2];      // zero slot at 715
    __shared__ float4 ampB[221][2];      // zero slot at 220

    const int b0 = blockIdx.x * 4;
    const int tid = threadIdx.x;
    const int r = tid / 5, c = tid % 5;

    if (tid < 50) {
        const float TP = 6.28318530717958647692f;
        float s0, c0, s1, c1, s2, c2, s3, c3;
        sincosf(TP * x[(b0 + 0) * MODES + c], &s0, &c0);
        sincosf(TP * x[(b0 + 1) * MODES + c], &s1, &c1);
        sincosf(TP * x[(b0 + 2) * MODES + c], &s2, &c2);
        sincosf(TP * x[(b0 + 3) * MODES + c], &s3, &c3);
        float2 m = g_M[r][c];
        Ua[r][c] = make_float4(m.x * c0 - m.y * s0, m.x * s0 + m.y * c0,
                               m.x * c1 - m.y * s1, m.x * s1 + m.y * c1);
        Ub[r][c] = make_float4(m.x * c2 - m.y * s2, m.x * s2 + m.y * c2,
                               m.x * c3 - m.y * s3, m.x * s3 + m.y * c3);
    }
    if (tid == 0) {
        ampA[0][0] = make_float4(1.f, 0.f, 1.f, 0.f);
        ampA[0][1] = make_float4(1.f, 0.f, 1.f, 0.f);
        float4 z = make_float4(0.f, 0.f, 0.f, 0.f);
        ampA[715][0] = z; ampA[715][1] = z;
        ampB[220][0] = z; ampB[220][1] = z;
    }
    __syncthreads();

    slos4<1>(ampA, ampB, g_tbl32 + 0,   10,  tid, Ua, Ub, 0);
    slos4<2>(ampB, ampA, g_tbl32 + 10,  55,  tid, Ua, Ub, 1);
    slos4<3>(ampA, ampB, g_tbl32 + 120, 220, tid, Ua, Ub, 2);
    slos4<4>(ampB, ampA, g_tbl32 + 780, 715, tid, Ua, Ub, 3);

    // level 4 fused with c2 * |.|^2 -> global (no LDS round-trip)
    float* po0 = g_probs + (size_t)b0 * NST5;
    float* po1 = po0 + NST5;
    float* po2 = po1 + NST5;
    float* po3 = po2 + NST5;
    const unsigned* tk = g_tbl32 + 3640;
    for (int t = tid; t < NST5; t += 256) {
        float ax0 = 0.f, ay0 = 0.f, ax1 = 0.f, ay1 = 0.f;
        float ax2 = 0.f, ay2 = 0.f, ax3 = 0.f, ay3 = 0.f;
        const unsigned* tt = tk + (size_t)t * 5;
        #pragma unroll
        for (int sl = 0; sl < 5; sl++) {
            unsigned e = tt[sl];
            int idx = e & 0xFFF;
            int j = (e >> 12) & 0xF;
            float4 a01 = ampA[idx][0];
            float4 a23 = ampA[idx][1];
            float4 u01 = Ua[j][4];
            float4 u23 = Ub[j][4];
            ax0 = fmaf(u01.x, a01.x, ax0); ax0 = fmaf(-u01.y, a01.y, ax0);
            ay0 = fmaf(u01.x, a01.y, ay0); ay0 = fmaf( u01.y, a01.x, ay0);
            ax1 = fmaf(u01.z, a01.z, ax1); ax1 = fmaf(-u01.w, a01.w, ax1);
            ay1 = fmaf(u01.z, a01.w, ay1); ay1 = fmaf( u01.w, a01.z, ay1);
            ax2 = fmaf(u23.x, a23.x, ax2); ax2 = fmaf(-u23.y, a23.y, ax2);
            ay2 = fmaf(u23.x, a23.y, ay2); ay2 = fmaf( u23.y, a23.x, ay2);
            ax3 = fmaf(u23.z, a23.z, ax3); ax3 = fmaf(-u23.w, a23.w, ax3);
            ay3 = fmaf(u23.z, a23.w, ay3); ay3 = fmaf( u23.w, a23.z, ay3);
        }
        float c2v = g_c2[t];
        po0[t] = c2v * (ax0 * ax0 + ay0 * ay0);
        po1[t] = c2v * (ax1 * ax1 + ay1 * ay1);
        po2[t] = c2v * (ax2 * ax2 + ay2 * ay2);
        po3[t] = c2v * (ax3 * ax3 + ay3 * ay3);
    }
}

// ---------- GEMM: g_part[kc] = P[64-row tile] x W  (LDS-tiled, K split x16) ----------
// (Round-15 form: scalar broadcast P reads; the all-float4 variant regressed.)
__global__ __launch_bounds__(256)
void k_gemm2(const float* __restrict__ W) {
    __shared__ float P_lds[64][68];
    __shared__ float W_lds[64][68];

    const int bm = blockIdx.x;
    const int kc = blockIdx.y;
    const int r0 = bm * 64;
    const int ks = kc * KCHUNK;
    const int ke = (ks + KCHUNK < NST5) ? ks + KCHUNK : NST5;

    const int tid = threadIdx.x;
    const int rg = tid >> 4;
    const int cg = tid & 15;
    const int srow = tid >> 4;
    const int sc4 = (tid & 15) * 4;

    float acc[4][4];
    #pragma unroll
    for (int i = 0; i < 4; i++)
        #pragma unroll
        for (int j = 0; j < 4; j++) acc[i][j] = 0.f;

    for (int k0 = ks; k0 < ke; k0 += 64) {
        const int kw = ke - k0;
        __syncthreads();
        #pragma unroll
        for (int p = 0; p < 4; p++) {
            int row = p * 16 + srow;
            float4 v = make_float4(0.f, 0.f, 0.f, 0.f);
            if (sc4 < kw) {
                const float* src = &g_probs[(size_t)(r0 + row) * NST5 + k0 + sc4];
                if (sc4 + 4 <= kw) {
                    v = *(const float4*)src;
                } else {
                    float tmp[4] = {0.f, 0.f, 0.f, 0.f};
                    for (int i = 0; i < kw - sc4; i++) tmp[i] = src[i];
                    v = *(const float4*)tmp;
                }
            }
            *(float4*)&P_lds[row][sc4] = v;
        }
        #pragma unroll
        for (int p = 0; p < 4; p++) {
            int krow = p * 16 + srow;
            float4 v = make_float4(0.f, 0.f, 0.f, 0.f);
            if (krow < kw)
                v = *(const float4*)&W[(size_t)(k0 + krow) * 64 + sc4];
            *(float4*)&W_lds[krow][sc4] = v;
        }
        __syncthreads();

        #pragma unroll 4
        for (int kk = 0; kk < 64; kk++) {
            float4 wv = *(const float4*)&W_lds[kk][cg * 4];
            float pr[4];
            #pragma unroll
            for (int i = 0; i < 4; i++) pr[i] = P_lds[rg * 4 + i][kk];
            #pragma unroll
            for (int i = 0; i < 4; i++) {
                acc[i][0] = fmaf(pr[i], wv.x, acc[i][0]);
                acc[i][1] = fmaf(pr[i], wv.y, acc[i][1]);
                acc[i][2] = fmaf(pr[i], wv.z, acc[i][2]);
                acc[i][3] = fmaf(pr[i], wv.w, acc[i][3]);
            }
        }
    }

    float* po = g_part + ((size_t)kc * BATCH + r0) * 64;
    #pragma unroll
    for (int i = 0; i < 4; i++) {
        float4 v = make_float4(acc[i][0], acc[i][1], acc[i][2], acc[i][3]);
        *(float4*)&po[(size_t)(rg * 4 + i) * 64 + cg * 4] = v;
    }
}

// ---------- reduce KSPLIT partials + bias ----------
__global__ __launch_bounds__(256)
void k_reduce(const float* __restrict__ bias, float* __restrict__ out) {
    int i = blockIdx.x * 256 + threadIdx.x;
    const int TOT = BATCH * 64;
    if (i < TOT) {
        float v = bias[i & 63];
        #pragma unroll
        for (int m = 0; m < KSPLIT; m++) v += g_part[(size_t)m * TOT + i];
        out[i] = v;
    }
}

extern "C" void kernel_launch(void* const* d_in, const int* in_sizes, int n_in,
                              void* d_out, int out_size, void* d_ws, size_t ws_size,
                              hipStream_t stream) {
    const float* x     = (const float*)d_in[0];
    const float* theta = (const float*)d_in[1];
    const float* W     = (const float*)d_in[2];
    const float* bias  = (const float*)d_in[3];
    float* out = (float*)d_out;
    (void)d_ws; (void)ws_size; (void)in_sizes; (void)n_in; (void)out_size;

    k_tables<<<12, 256, 0, stream>>>();
    k_prep<<<1, 64, 0, stream>>>(theta);
    k_slos<<<BATCH / 4, 256, 0, stream>>>(x);
    k_gemm2<<<dim3(64, KSPLIT), 256, 0, stream>>>(W);
    k_reduce<<<1024, 256, 0, stream>>>(bias, out);
}